// Round 1
// baseline (219.654 us; speedup 1.0000x reference)
//
#include <hip/hip_runtime.h>

// Problem dims
constexpr int SEQ   = 2048;
constexpr int BATCH = 2;
constexpr int EMB   = 1024;
constexpr int NH    = 16;
constexpr int HDIM  = 64;
constexpr int MROWS = SEQ * BATCH;   // 4096
constexpr int KDIM  = EMB;           // 1024
constexpr int NCOLS = 3 * EMB;       // 3072

typedef __bf16 bf16x8 __attribute__((ext_vector_type(8)));
typedef __bf16 bf16x4 __attribute__((ext_vector_type(4)));
typedef float  f32x4  __attribute__((ext_vector_type(4)));

// ---------------------------------------------------------------------------
// fp32 -> bf16 cast, vectorized (float4 in, 4x bf16 out)
// ---------------------------------------------------------------------------
__global__ __launch_bounds__(256) void cvt_f32_bf16(
    const float* __restrict__ src, __bf16* __restrict__ dst, int n4) {
  int stride = gridDim.x * blockDim.x;
  for (int i = blockIdx.x * blockDim.x + threadIdx.x; i < n4; i += stride) {
    float4 v = reinterpret_cast<const float4*>(src)[i];
    bf16x4 o;
    o[0] = (__bf16)v.x; o[1] = (__bf16)v.y; o[2] = (__bf16)v.z; o[3] = (__bf16)v.w;
    reinterpret_cast<bf16x4*>(dst)[i] = o;
  }
}

// ---------------------------------------------------------------------------
// QKV projection: Xb[M,K] * Wb[N,K]^T + bias -> scatter into Qb/Kb (b,h,s,d)
// and Vt (b,h,d,s). Q pre-scaled by 0.125*log2(e) so attention uses exp2.
// 128x128 tile, 4 waves, 4x4 16x16x32 frags per wave, BK=32.
// ---------------------------------------------------------------------------
__global__ __launch_bounds__(256) void qkv_gemm(
    const __bf16* __restrict__ Xb, const __bf16* __restrict__ Wb,
    const float* __restrict__ bqkv,
    __bf16* __restrict__ Qb, __bf16* __restrict__ Kb, __bf16* __restrict__ Vt) {
  __shared__ __attribute__((aligned(16))) __bf16 Al[128][40];  // 32 data + 8 pad
  __shared__ __attribute__((aligned(16))) __bf16 Bl[128][40];

  const int tid  = threadIdx.x;
  const int lane = tid & 63;
  const int w    = tid >> 6;
  const int wm   = w >> 1, wn = w & 1;
  const int m0   = blockIdx.y * 128;
  const int n0   = blockIdx.x * 128;

  f32x4 acc[4][4] = {};

  for (int kt = 0; kt < KDIM / 32; ++kt) {
    const int k0 = kt * 32;
    // stage A and B tiles (each thread: 2x 16B per tile)
#pragma unroll
    for (int i = 0; i < 2; ++i) {
      int u = tid + i * 256;        // 0..511 16B-chunks
      int row = u >> 2, c = u & 3;  // 128 rows x 4 chunks of 8 bf16
      *reinterpret_cast<bf16x8*>(&Al[row][c * 8]) =
          *reinterpret_cast<const bf16x8*>(&Xb[(size_t)(m0 + row) * KDIM + k0 + c * 8]);
      *reinterpret_cast<bf16x8*>(&Bl[row][c * 8]) =
          *reinterpret_cast<const bf16x8*>(&Wb[(size_t)(n0 + row) * KDIM + k0 + c * 8]);
    }
    __syncthreads();

    bf16x8 af[4], bfr[4];
#pragma unroll
    for (int i = 0; i < 4; ++i)
      af[i] = *reinterpret_cast<const bf16x8*>(&Al[wm * 64 + i * 16 + (lane & 15)][(lane >> 4) * 8]);
#pragma unroll
    for (int j = 0; j < 4; ++j)
      bfr[j] = *reinterpret_cast<const bf16x8*>(&Bl[wn * 64 + j * 16 + (lane & 15)][(lane >> 4) * 8]);
#pragma unroll
    for (int i = 0; i < 4; ++i)
#pragma unroll
      for (int j = 0; j < 4; ++j)
        acc[i][j] = __builtin_amdgcn_mfma_f32_16x16x32_bf16(af[i], bfr[j], acc[i][j], 0, 0, 0);
    __syncthreads();
  }

  // epilogue: bias add + scatter to Q/K/Vt in bf16
  const float QSCALE = 0.18033688011112042f;  // 0.125 * log2(e)
#pragma unroll
  for (int j = 0; j < 4; ++j) {
    const int f    = n0 + wn * 64 + j * 16 + (lane & 15);
    const float bias = bqkv[f];
    const int sec  = f >> 10;          // 0=q 1=k 2=v
    const int hd   = f & 1023;
    const int h    = hd >> 6, d = hd & 63;
#pragma unroll
    for (int i = 0; i < 4; ++i) {
#pragma unroll
      for (int r = 0; r < 4; ++r) {
        const int mm = m0 + wm * 64 + i * 16 + (lane >> 4) * 4 + r;
        const int s_ = mm >> 1, b_ = mm & 1;
        const int bh = b_ * NH + h;
        const float val = acc[i][j][r] + bias;
        if (sec == 0) {
          Qb[((size_t)bh * SEQ + s_) * HDIM + d] = (__bf16)(val * QSCALE);
        } else if (sec == 1) {
          Kb[((size_t)bh * SEQ + s_) * HDIM + d] = (__bf16)val;
        } else {
          Vt[((size_t)bh * HDIM + d) * SEQ + s_] = (__bf16)val;
        }
      }
    }
  }
}

// ---------------------------------------------------------------------------
// Flash attention: grid (SEQ/128, BATCH*NH), 8 waves x 16 q-rows, TBLK=32.
// K/V tiles staged in padded LDS (shared by all waves); online softmax in
// exp2 domain (Q pre-scaled); P transposed through per-wave LDS tile.
// ---------------------------------------------------------------------------
__global__ __launch_bounds__(512) void attn_fwd(
    const __bf16* __restrict__ Qb, const __bf16* __restrict__ Kb,
    const __bf16* __restrict__ Vt, float* __restrict__ out) {
  __shared__ __attribute__((aligned(16))) __bf16 Kl[32][72];     // [t][d], pad 64->72
  __shared__ __attribute__((aligned(16))) __bf16 Vl[64][40];     // [d][t], pad 32->40
  __shared__ __attribute__((aligned(16))) __bf16 Pl[8][16][40];  // per-wave P^T staging

  const int tid  = threadIdx.x;
  const int lane = tid & 63;
  const int w    = tid >> 6;
  const int bh   = blockIdx.y;
  const int b_   = bh >> 4, h = bh & 15;
  const int q0   = blockIdx.x * 128 + w * 16;

  const __bf16* Qp = Qb + (size_t)bh * SEQ * HDIM;
  const __bf16* Kp = Kb + (size_t)bh * SEQ * HDIM;
  const __bf16* Vp = Vt + (size_t)bh * HDIM * SEQ;

  // persistent Q fragments (16 rows x 64 d = 2 frags of K=32)
  const int qrow = q0 + (lane & 15);
  bf16x8 qa0 = *reinterpret_cast<const bf16x8*>(&Qp[(size_t)qrow * HDIM + (lane >> 4) * 8]);
  bf16x8 qa1 = *reinterpret_cast<const bf16x8*>(&Qp[(size_t)qrow * HDIM + 32 + (lane >> 4) * 8]);

  f32x4 acc[4] = {};
  float m[4] = {-1e30f, -1e30f, -1e30f, -1e30f};
  float l[4] = {0.f, 0.f, 0.f, 0.f};

  for (int t0 = 0; t0 < SEQ; t0 += 32) {
    // cooperative staging: 512 threads x one 16B chunk each
    if (tid < 256) {
      int row = tid >> 3, c = tid & 7;  // K tile 32x64
      *reinterpret_cast<bf16x8*>(&Kl[row][c * 8]) =
          *reinterpret_cast<const bf16x8*>(&Kp[(size_t)(t0 + row) * HDIM + c * 8]);
    } else {
      int u = tid - 256;
      int dd = u >> 2, c = u & 3;       // V^T tile 64x32
      *reinterpret_cast<bf16x8*>(&Vl[dd][c * 8]) =
          *reinterpret_cast<const bf16x8*>(&Vp[(size_t)dd * SEQ + t0 + c * 8]);
    }
    __syncthreads();

    // scores: 16q x 32t (two 16-col frags)
    f32x4 s0 = {}, s1 = {};
    {
      bf16x8 kf;
      kf = *reinterpret_cast<const bf16x8*>(&Kl[lane & 15][(lane >> 4) * 8]);
      s0 = __builtin_amdgcn_mfma_f32_16x16x32_bf16(qa0, kf, s0, 0, 0, 0);
      kf = *reinterpret_cast<const bf16x8*>(&Kl[lane & 15][32 + (lane >> 4) * 8]);
      s0 = __builtin_amdgcn_mfma_f32_16x16x32_bf16(qa1, kf, s0, 0, 0, 0);
      kf = *reinterpret_cast<const bf16x8*>(&Kl[16 + (lane & 15)][(lane >> 4) * 8]);
      s1 = __builtin_amdgcn_mfma_f32_16x16x32_bf16(qa0, kf, s1, 0, 0, 0);
      kf = *reinterpret_cast<const bf16x8*>(&Kl[16 + (lane & 15)][32 + (lane >> 4) * 8]);
      s1 = __builtin_amdgcn_mfma_f32_16x16x32_bf16(qa1, kf, s1, 0, 0, 0);
    }

    // online softmax (exp2 domain; scores already carry log2e factor)
#pragma unroll
    for (int r = 0; r < 4; ++r) {
      float t = fmaxf(s0[r], s1[r]);
      t = fmaxf(t, __shfl_xor(t, 1));
      t = fmaxf(t, __shfl_xor(t, 2));
      t = fmaxf(t, __shfl_xor(t, 4));
      t = fmaxf(t, __shfl_xor(t, 8));
      const float mnew  = fmaxf(m[r], t);
      const float alpha = exp2f(m[r] - mnew);
      const float p0 = exp2f(s0[r] - mnew);
      const float p1 = exp2f(s1[r] - mnew);
      m[r] = mnew;
      float rs = p0 + p1;
      rs += __shfl_xor(rs, 1);
      rs += __shfl_xor(rs, 2);
      rs += __shfl_xor(rs, 4);
      rs += __shfl_xor(rs, 8);
      l[r] = l[r] * alpha + rs;
      acc[0][r] *= alpha; acc[1][r] *= alpha; acc[2][r] *= alpha; acc[3][r] *= alpha;
      const int q = (lane >> 4) * 4 + r;
      Pl[w][q][(lane & 15)]      = (__bf16)p0;
      Pl[w][q][16 + (lane & 15)] = (__bf16)p1;
    }

    // PV: one K=32 MFMA per 16-wide d block
    bf16x8 pa = *reinterpret_cast<const bf16x8*>(&Pl[w][lane & 15][(lane >> 4) * 8]);
#pragma unroll
    for (int c2 = 0; c2 < 4; ++c2) {
      bf16x8 vf = *reinterpret_cast<const bf16x8*>(&Vl[c2 * 16 + (lane & 15)][(lane >> 4) * 8]);
      acc[c2] = __builtin_amdgcn_mfma_f32_16x16x32_bf16(pa, vf, acc[c2], 0, 0, 0);
    }
    __syncthreads();
  }

  // epilogue: normalize + store fp32 [s][b][e]
#pragma unroll
  for (int r = 0; r < 4; ++r) {
    const int s_  = q0 + (lane >> 4) * 4 + r;
    const float inv = 1.0f / l[r];
#pragma unroll
    for (int c2 = 0; c2 < 4; ++c2) {
      out[((size_t)s_ * BATCH + b_) * EMB + h * HDIM + c2 * 16 + (lane & 15)] = acc[c2][r] * inv;
    }
  }
}

// ---------------------------------------------------------------------------
extern "C" void kernel_launch(void* const* d_in, const int* in_sizes, int n_in,
                              void* d_out, int out_size, void* d_ws, size_t ws_size,
                              hipStream_t stream) {
  (void)in_sizes; (void)n_in; (void)out_size; (void)ws_size;
  const float* x    = (const float*)d_in[0];
  const float* Wqkv = (const float*)d_in[1];
  const float* bias = (const float*)d_in[2];
  float* out = (float*)d_out;

  char* ws = (char*)d_ws;
  __bf16* Xb = (__bf16*)(ws);                 //  8 MB  [M][K]
  __bf16* Wb = (__bf16*)(ws + 8388608);       //  6 MB  [N][K]
  __bf16* Qb = (__bf16*)(ws + 14680064);      //  8 MB  [b,h,s,d] (pre-scaled)
  __bf16* Kb = (__bf16*)(ws + 23068672);      //  8 MB  [b,h,s,d]
  __bf16* Vt = (__bf16*)(ws + 31457280);      //  8 MB  [b,h,d,s]

  cvt_f32_bf16<<<dim3(1024), dim3(256), 0, stream>>>(x, Xb, (MROWS * KDIM) / 4);
  cvt_f32_bf16<<<dim3(768), dim3(256), 0, stream>>>(Wqkv, Wb, (NCOLS * KDIM) / 4);
  qkv_gemm<<<dim3(NCOLS / 128, MROWS / 128), dim3(256), 0, stream>>>(Xb, Wb, bias, Qb, Kb, Vt);
  attn_fwd<<<dim3(SEQ / 128, BATCH * NH), dim3(512), 0, stream>>>(Qb, Kb, Vt, out);
}

// Round 2
// 117.538 us; speedup vs baseline: 1.8688x; 1.8688x over previous
//
#include <hip/hip_runtime.h>

// Problem dims
constexpr int SEQ   = 2048;
constexpr int BATCH = 2;
constexpr int EMB   = 1024;
constexpr int NH    = 16;
constexpr int HDIM  = 64;
constexpr int MROWS = SEQ * BATCH;   // 4096
constexpr int KDIM  = EMB;           // 1024
constexpr int NCOLS = 3 * EMB;       // 3072

typedef __bf16 bf16x8 __attribute__((ext_vector_type(8)));
typedef __bf16 bf16x4 __attribute__((ext_vector_type(4)));
typedef float  f32x4  __attribute__((ext_vector_type(4)));
typedef float  f32x16 __attribute__((ext_vector_type(16)));
typedef unsigned int u32;
typedef unsigned int u32x4 __attribute__((ext_vector_type(4)));

__device__ __forceinline__ u32 cvt_pk_bf16(float lo, float hi) {
  u32 r;
  asm("v_cvt_pk_bf16_f32 %0, %1, %2" : "=v"(r) : "v"(lo), "v"(hi));
  return r;
}
__device__ __forceinline__ void pl32_swap(u32& a, u32& b) {
  asm("v_permlane32_swap_b32 %0, %1" : "+v"(a), "+v"(b));
}

// ---------------------------------------------------------------------------
// fp32 -> bf16 cast, vectorized (float4 in, 4x bf16 out)
// ---------------------------------------------------------------------------
__global__ __launch_bounds__(256) void cvt_f32_bf16(
    const float* __restrict__ src, __bf16* __restrict__ dst, int n4) {
  int stride = gridDim.x * blockDim.x;
  for (int i = blockIdx.x * blockDim.x + threadIdx.x; i < n4; i += stride) {
    float4 v = reinterpret_cast<const float4*>(src)[i];
    bf16x4 o;
    o[0] = (__bf16)v.x; o[1] = (__bf16)v.y; o[2] = (__bf16)v.z; o[3] = (__bf16)v.w;
    reinterpret_cast<bf16x4*>(dst)[i] = o;
  }
}

// ---------------------------------------------------------------------------
// QKV projection (unchanged from R1): Xb[M,K] * Wb[N,K]^T + bias -> Qb/Kb/Vt.
// ---------------------------------------------------------------------------
__global__ __launch_bounds__(256) void qkv_gemm(
    const __bf16* __restrict__ Xb, const __bf16* __restrict__ Wb,
    const float* __restrict__ bqkv,
    __bf16* __restrict__ Qb, __bf16* __restrict__ Kb, __bf16* __restrict__ Vt) {
  __shared__ __attribute__((aligned(16))) __bf16 Al[128][40];
  __shared__ __attribute__((aligned(16))) __bf16 Bl[128][40];

  const int tid  = threadIdx.x;
  const int lane = tid & 63;
  const int w    = tid >> 6;
  const int wm   = w >> 1, wn = w & 1;
  const int m0   = blockIdx.y * 128;
  const int n0   = blockIdx.x * 128;

  f32x4 acc[4][4] = {};

  for (int kt = 0; kt < KDIM / 32; ++kt) {
    const int k0 = kt * 32;
#pragma unroll
    for (int i = 0; i < 2; ++i) {
      int u = tid + i * 256;
      int row = u >> 2, c = u & 3;
      *reinterpret_cast<bf16x8*>(&Al[row][c * 8]) =
          *reinterpret_cast<const bf16x8*>(&Xb[(size_t)(m0 + row) * KDIM + k0 + c * 8]);
      *reinterpret_cast<bf16x8*>(&Bl[row][c * 8]) =
          *reinterpret_cast<const bf16x8*>(&Wb[(size_t)(n0 + row) * KDIM + k0 + c * 8]);
    }
    __syncthreads();

    bf16x8 af[4], bfr[4];
#pragma unroll
    for (int i = 0; i < 4; ++i)
      af[i] = *reinterpret_cast<const bf16x8*>(&Al[wm * 64 + i * 16 + (lane & 15)][(lane >> 4) * 8]);
#pragma unroll
    for (int j = 0; j < 4; ++j)
      bfr[j] = *reinterpret_cast<const bf16x8*>(&Bl[wn * 64 + j * 16 + (lane & 15)][(lane >> 4) * 8]);
#pragma unroll
    for (int i = 0; i < 4; ++i)
#pragma unroll
      for (int j = 0; j < 4; ++j)
        acc[i][j] = __builtin_amdgcn_mfma_f32_16x16x32_bf16(af[i], bfr[j], acc[i][j], 0, 0, 0);
    __syncthreads();
  }

  const float QSCALE = 0.18033688011112042f;  // 0.125 * log2(e)
#pragma unroll
  for (int j = 0; j < 4; ++j) {
    const int f    = n0 + wn * 64 + j * 16 + (lane & 15);
    const float bias = bqkv[f];
    const int sec  = f >> 10;
    const int hd   = f & 1023;
    const int h    = hd >> 6, d = hd & 63;
#pragma unroll
    for (int i = 0; i < 4; ++i) {
#pragma unroll
      for (int r = 0; r < 4; ++r) {
        const int mm = m0 + wm * 64 + i * 16 + (lane >> 4) * 4 + r;
        const int s_ = mm >> 1, b_ = mm & 1;
        const int bh = b_ * NH + h;
        const float val = acc[i][j][r] + bias;
        if (sec == 0) {
          Qb[((size_t)bh * SEQ + s_) * HDIM + d] = (__bf16)(val * QSCALE);
        } else if (sec == 1) {
          Kb[((size_t)bh * SEQ + s_) * HDIM + d] = (__bf16)val;
        } else {
          Vt[((size_t)bh * HDIM + d) * SEQ + s_] = (__bf16)val;
        }
      }
    }
  }
}

// ---------------------------------------------------------------------------
// Flash attention, m214-style: 8 waves x 32 q-rows (block = 256 q), KVBLK=64,
// swapped QK^T (S = K·Q^T) and swapped PV (O^T = V^T·P^T) with 32x32x16 MFMA.
// Softmax fully in-register (row is lane-local, q = lane&31); P->bf16 via
// v_cvt_pk_bf16_f32 + v_permlane32_swap_b32. K/V LDS tiles XOR-swizzled.
// ---------------------------------------------------------------------------
__global__ __launch_bounds__(512) void attn_fwd(
    const __bf16* __restrict__ Qb, const __bf16* __restrict__ Kb,
    const __bf16* __restrict__ Vt, float* __restrict__ out) {
  __shared__ __attribute__((aligned(16))) __bf16 lds[8192];  // K: [0,4096), V^T: [4096,8192)
  __bf16* Kl = lds;
  __bf16* Vl = lds + 4096;

  const int tid  = threadIdx.x;
  const int lane = tid & 63;
  const int w    = tid >> 6;
  const int lq   = lane & 31;   // q-col (and d-row) index
  const int hi   = lane >> 5;
  const int bh   = blockIdx.y;
  const int b_   = bh >> 4, h = bh & 15;
  const int q0   = blockIdx.x * 256 + w * 32;

  const __bf16* Qp = Qb + (size_t)bh * SEQ * HDIM;
  const __bf16* Kp = Kb + (size_t)bh * SEQ * HDIM;
  const __bf16* Vp = Vt + (size_t)bh * HDIM * SEQ;

  // Q persistent in registers as QK^T B-operand: col q=lane&31, k(d)=ks*16+hi*8+j
  bf16x8 qf[4];
#pragma unroll
  for (int ks = 0; ks < 4; ++ks)
    qf[ks] = *reinterpret_cast<const bf16x8*>(&Qp[(size_t)(q0 + lq) * HDIM + ks * 16 + hi * 8]);

  f32x16 acc0 = {}, acc1 = {};
  float m = -1e30f, l = 0.f;

  // staging: 512 threads x one 16B chunk per tile (K and V each 64x64 bf16)
  const int srow = tid >> 3;                 // 0..63
  const int scol = (tid & 7) * 8;            // bf16 col
  const int sidx = srow * 64 + (scol ^ ((srow & 7) << 3));  // XOR-swizzled

  for (int t0 = 0; t0 < SEQ; t0 += 64) {
    __syncthreads();
    *reinterpret_cast<bf16x8*>(&Kl[sidx]) =
        *reinterpret_cast<const bf16x8*>(&Kp[(size_t)(t0 + srow) * HDIM + scol]);
    *reinterpret_cast<bf16x8*>(&Vl[sidx]) =
        *reinterpret_cast<const bf16x8*>(&Vp[(size_t)srow * SEQ + t0 + scol]);
    __syncthreads();

    // ---- S = K·Q^T : two 32x32 t-blocks, 4 k-steps over d ----
    f32x16 S0 = {}, S1 = {};
#pragma unroll
    for (int ks = 0; ks < 4; ++ks) {
      const int colb = ks * 16 + hi * 8;
      bf16x8 k0 = *reinterpret_cast<const bf16x8*>(&Kl[lq * 64        + (colb ^ ((lq & 7) << 3))]);
      bf16x8 k1 = *reinterpret_cast<const bf16x8*>(&Kl[(32 + lq) * 64 + (colb ^ ((lq & 7) << 3))]);
      S0 = __builtin_amdgcn_mfma_f32_32x32x16_bf16(k0, qf[ks], S0, 0, 0, 0);
      S1 = __builtin_amdgcn_mfma_f32_32x32x16_bf16(k1, qf[ks], S1, 0, 0, 0);
    }

    // ---- online softmax, in-register (exp2 domain) ----
    float pmax = S0[0];
#pragma unroll
    for (int i = 1; i < 16; ++i) pmax = fmaxf(pmax, S0[i]);
#pragma unroll
    for (int i = 0; i < 16; ++i) pmax = fmaxf(pmax, S1[i]);
    pmax = fmaxf(pmax, __shfl_xor(pmax, 32));
    const float mnew  = fmaxf(m, pmax);
    const float alpha = __builtin_amdgcn_exp2f(m - mnew);
    m = mnew;
    float rs = 0.f;
#pragma unroll
    for (int i = 0; i < 16; ++i) { S0[i] = __builtin_amdgcn_exp2f(S0[i] - mnew); rs += S0[i]; }
#pragma unroll
    for (int i = 0; i < 16; ++i) { S1[i] = __builtin_amdgcn_exp2f(S1[i] - mnew); rs += S1[i]; }
    l = l * alpha + rs;
#pragma unroll
    for (int i = 0; i < 16; ++i) { acc0[i] *= alpha; acc1[i] *= alpha; }

    // ---- P (f32, rows t) -> bf16 B-fragments for PV: col q, k = t ----
    // reg r of S holds t = (r&3) + 8*(r>>2) + 4*hi; cvt_pk + permlane32_swap
    // redistributes to B-frag order k = hi*8 + j.
    bf16x8 pw[4];
    {
      auto mk = [&](const f32x16& P, bf16x8* dst) {
#pragma unroll
        for (int kk = 0; kk < 2; ++kk) {
          u32 a0 = cvt_pk_bf16(P[kk * 8 + 0], P[kk * 8 + 1]);
          u32 b0 = cvt_pk_bf16(P[kk * 8 + 4], P[kk * 8 + 5]);
          u32 a1 = cvt_pk_bf16(P[kk * 8 + 2], P[kk * 8 + 3]);
          u32 b1 = cvt_pk_bf16(P[kk * 8 + 6], P[kk * 8 + 7]);
          pl32_swap(a0, b0);
          pl32_swap(a1, b1);
          u32x4 wv; wv[0] = a0; wv[1] = a1; wv[2] = b0; wv[3] = b1;
          dst[kk] = __builtin_bit_cast(bf16x8, wv);
        }
      };
      mk(S0, &pw[0]);  // t 0..31
      mk(S1, &pw[2]);  // t 32..63
    }

    // ---- O^T += V^T · P^T : 2 d-blocks x 4 k-steps over t ----
#pragma unroll
    for (int ks = 0; ks < 4; ++ks) {
      const int colb = ks * 16 + hi * 8;
      bf16x8 v0 = *reinterpret_cast<const bf16x8*>(&Vl[lq * 64        + (colb ^ ((lq & 7) << 3))]);
      bf16x8 v1 = *reinterpret_cast<const bf16x8*>(&Vl[(32 + lq) * 64 + (colb ^ ((lq & 7) << 3))]);
      acc0 = __builtin_amdgcn_mfma_f32_32x32x16_bf16(v0, pw[ks], acc0, 0, 0, 0);
      acc1 = __builtin_amdgcn_mfma_f32_32x32x16_bf16(v1, pw[ks], acc1, 0, 0, 0);
    }
  }

  // ---- epilogue: combine l across lane halves, normalize, store fp32 ----
  l += __shfl_xor(l, 32);
  const float inv = 1.0f / l;
  const int s_ = q0 + lq;
  float* op = out + ((size_t)s_ * BATCH + b_) * EMB + h * HDIM;
#pragma unroll
  for (int rr = 0; rr < 4; ++rr) {
    float4 o0 = {acc0[4 * rr] * inv, acc0[4 * rr + 1] * inv,
                 acc0[4 * rr + 2] * inv, acc0[4 * rr + 3] * inv};
    *reinterpret_cast<float4*>(&op[8 * rr + 4 * hi]) = o0;
    float4 o1 = {acc1[4 * rr] * inv, acc1[4 * rr + 1] * inv,
                 acc1[4 * rr + 2] * inv, acc1[4 * rr + 3] * inv};
    *reinterpret_cast<float4*>(&op[8 * rr + 4 * hi + 32]) = o1;
  }
}

// ---------------------------------------------------------------------------
extern "C" void kernel_launch(void* const* d_in, const int* in_sizes, int n_in,
                              void* d_out, int out_size, void* d_ws, size_t ws_size,
                              hipStream_t stream) {
  (void)in_sizes; (void)n_in; (void)out_size; (void)ws_size;
  const float* x    = (const float*)d_in[0];
  const float* Wqkv = (const float*)d_in[1];
  const float* bias = (const float*)d_in[2];
  float* out = (float*)d_out;

  char* ws = (char*)d_ws;
  __bf16* Xb = (__bf16*)(ws);                 //  8 MB  [M][K]
  __bf16* Wb = (__bf16*)(ws + 8388608);       //  6 MB  [N][K]
  __bf16* Qb = (__bf16*)(ws + 14680064);      //  8 MB  [b,h,s,d] (pre-scaled)
  __bf16* Kb = (__bf16*)(ws + 23068672);      //  8 MB  [b,h,s,d]
  __bf16* Vt = (__bf16*)(ws + 31457280);      //  8 MB  [b,h,d,s]

  cvt_f32_bf16<<<dim3(1024), dim3(256), 0, stream>>>(x, Xb, (MROWS * KDIM) / 4);
  cvt_f32_bf16<<<dim3(768), dim3(256), 0, stream>>>(Wqkv, Wb, (NCOLS * KDIM) / 4);
  qkv_gemm<<<dim3(NCOLS / 128, MROWS / 128), dim3(256), 0, stream>>>(Xb, Wb, bias, Qb, Kb, Vt);
  attn_fwd<<<dim3(SEQ / 256, BATCH * NH), dim3(512), 0, stream>>>(Qb, Kb, Vt, out);
}